// Round 6
// baseline (193.258 us; speedup 1.0000x reference)
//
#include <hip/hip_runtime.h>
#include <stdint.h>

#define BSz 4096   // B*S tokens
#define Ddim 1024
#define Fdim 4096
#define Edim 4
#define Rdim 4

typedef __attribute__((ext_vector_type(8))) short bf16x8;
typedef __attribute__((ext_vector_type(4))) float f32x4;

__device__ __forceinline__ unsigned short f2bf(float f) {
  union { float f; uint32_t u; } c; c.f = f;
  return (unsigned short)((c.u + 0x7fffu + ((c.u >> 16) & 1u)) >> 16);
}

// ---------------- zero d_out (deterministic base for split-K atomics) ----
__global__ __launch_bounds__(256) void zero_f32(float* __restrict__ p, int n4) {
  int i = blockIdx.x * 256 + threadIdx.x;
  if (i < n4) ((float4*)p)[i] = make_float4(0.f, 0.f, 0.f, 0.f);
}

// ---------------- fp32 -> bf16 conversion (vectorized) ----------------
__global__ __launch_bounds__(256) void cvt_kernel(const float* __restrict__ in,
                                                  unsigned short* __restrict__ out,
                                                  int n4) {
  int i = blockIdx.x * 256 + threadIdx.x;
  if (i < n4) {
    float4 v = ((const float4*)in)[i];
    ushort4 o;
    o.x = f2bf(v.x); o.y = f2bf(v.y); o.z = f2bf(v.z); o.w = f2bf(v.w);
    ((ushort4*)out)[i] = o;
  }
}

// ---------------- router: logits -> softmax -> top2 + lora_low ----------------
__global__ __launch_bounds__(256) void router_kernel(const float* __restrict__ x,
                                                     const float* __restrict__ Wg,
                                                     const float* __restrict__ bg,
                                                     const float* __restrict__ Aw,
                                                     float* __restrict__ meta) {
  __shared__ float xs[Ddim];
  __shared__ float dots[Edim + Edim * Rdim];
  const int t = blockIdx.x;
  const float4* xt = (const float4*)(x + (size_t)t * Ddim);
  for (int i = threadIdx.x; i < Ddim / 4; i += 256) ((float4*)xs)[i] = xt[i];
  __syncthreads();
  const int wave = threadIdx.x >> 6, lane = threadIdx.x & 63;
  for (int d = wave * 5; d < wave * 5 + 5; ++d) {
    const float* wrow = (d < Edim) ? (Wg + (size_t)d * Ddim)
                                   : (Aw + (size_t)(d - Edim) * Ddim);
    float s = 0.f;
    for (int i = lane; i < Ddim; i += 64) s += xs[i] * wrow[i];
    for (int off = 32; off; off >>= 1) s += __shfl_down(s, off);
    if (lane == 0) dots[d] = s;
  }
  __syncthreads();
  if (threadIdx.x == 0) {
    float p[Edim];
    float m = -1e30f;
    for (int e = 0; e < Edim; ++e) { p[e] = dots[e] + bg[e]; m = fmaxf(m, p[e]); }
    float sum = 0.f;
    for (int e = 0; e < Edim; ++e) { p[e] = expf(p[e] - m); sum += p[e]; }
    const float inv = 1.f / sum;
    for (int e = 0; e < Edim; ++e) p[e] *= inv;
    int e0 = 0;
    for (int e = 1; e < Edim; ++e) if (p[e] > p[e0]) e0 = e;
    int e1 = (e0 == 0) ? 1 : 0;
    for (int e = 0; e < Edim; ++e) if (e != e0 && p[e] > p[e1]) e1 = e;
    float* mt = meta + (size_t)t * 16;
    mt[0] = (float)e0; mt[1] = (float)e1; mt[2] = p[e0]; mt[3] = p[e1];
    for (int r = 0; r < Rdim; ++r) {
      mt[4 + r] = dots[Edim + e0 * Rdim + r];
      mt[8 + r] = dots[Edim + e1 * Rdim + r];
    }
    mt[12] = 0.f; mt[13] = 0.f; mt[14] = 0.f; mt[15] = 0.f;
  }
}

// ---------------- m97-structure NT bf16 GEMM ----------------
// C[M,N] = A[M,K] rows bm.. * B[N,K]^T rows bn.. over K-slice [kbase,+kslice).
// 128x128 tile, BK=64, 4 waves (2x2), single-buffered 32KB LDS, plain
// __syncthreads, compiler-scheduled (m97: 874-912 TF structure). ~3 blocks/CU
// provides cross-block latency hiding (m114). T2 XOR swizzle (slot^row&7)
// via pre-swizzled global source + swizzled ds_read (rule 21).
// EPI==0: fused MoE epilogue -> outg bf16 (LDS-repacked coalesced stores).
// EPI==1: f32 atomicAdd into outf (split-K).
template <int EPI>
__global__ __launch_bounds__(256, 3)
void gemm97(const unsigned short* __restrict__ Ag,
            const unsigned short* __restrict__ Bg,
            int K, int kslice, int Ncols,
            const float* __restrict__ meta,
            const float* __restrict__ B2,
            unsigned short* __restrict__ outg,
            float* __restrict__ outf) {
  constexpr int BK = 64;
  __shared__ __align__(16) unsigned short sA[128 * BK];   // 16 KB
  __shared__ __align__(16) unsigned short sB[128 * BK];   // 16 KB

  const int tid = threadIdx.x;
  const int lane = tid & 63;
  const int wave = tid >> 6;            // 0..3
  const int wr = wave >> 1, wc = wave & 1;
  const int l16 = lane & 15, lhi = lane >> 4;

  // XCD-aware bijective swizzle on the xy grid (nwg per z-slice % 8 == 0)
  const int nwg = gridDim.x * gridDim.y;
  const int lin = blockIdx.y * gridDim.x + blockIdx.x;
  const int cpx = nwg >> 3;
  const int swz = (lin & 7) * cpx + (lin >> 3);
  const int bx = swz % gridDim.x, by = swz / gridDim.x;
  const int bm = by * 128, bn = bx * 128;
  const int kbase = blockIdx.z * kslice;
  const int NT = kslice / BK;

  f32x4 acc[4][4] = {};

  // staging: 4 rounds per matrix; round rr covers rows tid/8 + rr*32.
  // LDS dest linear (tid*8 elems); global source column pre-swizzled by the
  // involution slot' = slot ^ (row & 7)  (slot = 16B chunk within 128B row).
  const int srow = tid >> 3;                                  // 0..31
  const int scol = ((tid & 7) ^ (srow & 7)) * 8;              // pre-swizzled col
  const int ldst = tid * 8;                                   // linear LDS elems

  // read-side swizzle: per-lane row parity bits (row & 7 == l16 & 7)
  const int xr = l16 & 7;

  for (int kt = 0; kt < NT; ++kt) {
    const int kof = kbase + kt * BK;
#pragma unroll
    for (int rr = 0; rr < 4; ++rr)
      __builtin_amdgcn_global_load_lds(
          (const __attribute__((address_space(1))) void*)(Ag + (size_t)(bm + srow + rr * 32) * K + kof + scol),
          (__attribute__((address_space(3))) void*)(sA + ldst + rr * 2048), 16, 0, 0);
#pragma unroll
    for (int rr = 0; rr < 4; ++rr)
      __builtin_amdgcn_global_load_lds(
          (const __attribute__((address_space(1))) void*)(Bg + (size_t)(bn + srow + rr * 32) * K + kof + scol),
          (__attribute__((address_space(3))) void*)(sB + ldst + rr * 2048), 16, 0, 0);
    __syncthreads();
#pragma unroll
    for (int kk = 0; kk < 2; ++kk) {
      bf16x8 af[4], bfv[4];
#pragma unroll
      for (int i = 0; i < 4; ++i) {
        const int ra = wr * 64 + i * 16 + l16;
        af[i] = *(const bf16x8*)(sA + ra * BK + ((kk * 4 + lhi) ^ xr) * 8);
        const int rb = wc * 64 + i * 16 + l16;
        bfv[i] = *(const bf16x8*)(sB + rb * BK + ((kk * 4 + lhi) ^ xr) * 8);
      }
#pragma unroll
      for (int i = 0; i < 4; ++i)
#pragma unroll
        for (int j = 0; j < 4; ++j)
          acc[i][j] = __builtin_amdgcn_mfma_f32_16x16x32_bf16(af[i], bfv[j], acc[i][j], 0, 0, 0);
    }
    __syncthreads();
  }

  if (EPI == 0) {
    // fused MoE epilogue: gv = sum_{e in top2} w_e*relu(acc + <ll_e,B2[e,f,:]>)
    // repack through LDS (reusing sA+sB as a 128x128 ushort tile) so global
    // stores are fully-coalesced 16B chunks (avoids 32B partial-sector RMW).
    unsigned short* tile = sA;   // sA(16KB)+sB(16KB) contiguous? not guaranteed;
    // use sA for rows 0..63 and sB for rows 64..127 instead (16KB each).
#pragma unroll
    for (int mi = 0; mi < 4; ++mi) {
#pragma unroll
      for (int r = 0; r < 4; ++r) {
        const int rowl = wr * 64 + mi * 16 + lhi * 4 + r;     // 0..127
        const int row = bm + rowl;
        const float* mt = meta + (size_t)row * 16;
        const int e0 = (int)mt[0], e1 = (int)mt[1];
        const float w0 = mt[2], w1 = mt[3];
        const float4 l0 = *(const float4*)(mt + 4);
        const float4 l1 = *(const float4*)(mt + 8);
        unsigned short* trow = (rowl < 64 ? sA + rowl * 128 : sB + (rowl - 64) * 128);
#pragma unroll
        for (int ni = 0; ni < 4; ++ni) {
          const int coll = wc * 64 + ni * 16 + l16;
          const int f = bn + coll;
          const float4 b0 = *(const float4*)(B2 + ((size_t)e0 * Fdim + f) * Rdim);
          const float4 b1 = *(const float4*)(B2 + ((size_t)e1 * Fdim + f) * Rdim);
          const float a = acc[mi][ni][r];
          const float lora0 = l0.x * b0.x + l0.y * b0.y + l0.z * b0.z + l0.w * b0.w;
          const float lora1 = l1.x * b1.x + l1.y * b1.y + l1.z * b1.z + l1.w * b1.w;
          const float gv = w0 * fmaxf(a + lora0, 0.f) + w1 * fmaxf(a + lora1, 0.f);
          trow[coll] = f2bf(gv);
        }
      }
    }
    __syncthreads();
    // coalesced copy: 128 rows x 256B; 16 threads/row x 16B; 8 rounds.
#pragma unroll
    for (int rnd = 0; rnd < 8; ++rnd) {
      const int idx = rnd * 256 + tid;          // 0..2047
      const int rowl = idx >> 4;                // 0..127
      const int chk = idx & 15;                 // 16B chunk
      const unsigned short* src = (rowl < 64 ? sA + rowl * 128 : sB + (rowl - 64) * 128) + chk * 8;
      *(bf16x8*)(outg + (size_t)(bm + rowl) * Fdim + bn + chk * 8) = *(const bf16x8*)src;
    }
  } else {
    // split-K partial: f32 atomic accumulate (16 lanes x 4B = 64B sectors)
#pragma unroll
    for (int mi = 0; mi < 4; ++mi)
#pragma unroll
      for (int ni = 0; ni < 4; ++ni)
#pragma unroll
        for (int r = 0; r < 4; ++r) {
          const int row = bm + wr * 64 + mi * 16 + lhi * 4 + r;
          const int col = bn + wc * 64 + ni * 16 + l16;
          unsafeAtomicAdd(&outf[(size_t)row * Ncols + col], acc[mi][ni][r]);
        }
  }
}

extern "C" void kernel_launch(void* const* d_in, const int* in_sizes, int n_in,
                              void* d_out, int out_size, void* d_ws, size_t ws_size,
                              hipStream_t stream) {
  const float* x  = (const float*)d_in[0];
  const float* Wg = (const float*)d_in[1];
  const float* bg = (const float*)d_in[2];
  const float* Wi = (const float*)d_in[3];
  const float* Wo = (const float*)d_in[4];
  const float* Aw = (const float*)d_in[5];
  const float* B2 = (const float*)d_in[6];
  float* out = (float*)d_out;

  // workspace layout (bf16 as ushort)
  unsigned short* xb  = (unsigned short*)d_ws;                 // [BSz][Ddim]   8 MB
  unsigned short* wib = xb  + (size_t)BSz  * Ddim;             // [Fdim][Ddim]  8 MB
  unsigned short* wob = wib + (size_t)Fdim * Ddim;             // [Ddim][Fdim]  8 MB
  unsigned short* g   = wob + (size_t)Ddim * Fdim;             // [BSz][Fdim]  32 MB
  float* meta = (float*)(g + (size_t)BSz * Fdim);              // [BSz][16]   256 KB

  zero_f32<<<BSz * Ddim / 4 / 256, 256, 0, stream>>>(out, BSz * Ddim / 4);

  const int n4x = BSz * Ddim / 4;   // == Fdim*Ddim/4 == Ddim*Fdim/4
  cvt_kernel<<<(n4x + 255) / 256, 256, 0, stream>>>(x,  xb,  n4x);
  cvt_kernel<<<(n4x + 255) / 256, 256, 0, stream>>>(Wi, wib, n4x);
  cvt_kernel<<<(n4x + 255) / 256, 256, 0, stream>>>(Wo, wob, n4x);

  router_kernel<<<BSz, 256, 0, stream>>>(x, Wg, bg, Aw, meta);

  // GEMM1: base = x * Wi^T, fused MoE epilogue -> g (bf16)
  // 128^2 tile, grid 32x32 = 1024 blocks (~3/CU co-resident), K=1024
  gemm97<0><<<dim3(Fdim / 128, BSz / 128, 1), 256, 0, stream>>>(
      xb, wib, Ddim, Ddim, Fdim, meta, B2, g, nullptr);

  // GEMM2: out = g * Wo^T, split-K x4 (slices of 1024), f32 atomics
  // grid 8x32x4 = 1024 blocks (~3/CU)
  gemm97<1><<<dim3(Ddim / 128, BSz / 128, 4), 256, 0, stream>>>(
      g, wob, Fdim, Fdim / 4, Ddim, nullptr, nullptr, nullptr, out);
}